// Round 11
// baseline (224.421 us; speedup 1.0000x reference)
//
#include <hip/hip_runtime.h>

// B=1, S=4096, D=1024, H=16, HD=64. I/O dtype self-detected (fp32 vs bf16).
#define SEQ 4096
#define DM  1024
#define NH  16
#define HDIM 64

typedef unsigned short u16;
typedef unsigned int   u32;
typedef __bf16 bf16x8 __attribute__((ext_vector_type(8)));
typedef float f32x4 __attribute__((ext_vector_type(4)));

__device__ __forceinline__ float bf2f(u16 u) {
    unsigned v = ((unsigned)u) << 16;
    float f;
    __builtin_memcpy(&f, &v, 4);
    return f;
}
__device__ __forceinline__ u16 f2bf(float f) {
    unsigned u;
    __builtin_memcpy(&u, &f, 4);
    return (u16)((u + 0x7fffu + ((u >> 16) & 1u)) >> 16);  // RNE
}
__device__ __forceinline__ u32 bfpack(float a, float b) {
    u32 ua, ub;
    __builtin_memcpy(&ua, &a, 4);
    __builtin_memcpy(&ub, &b, 4);
    return ((ua + 0x8000u) >> 16) | ((ub + 0x8000u) & 0xffff0000u);
}

// async global->LDS, 16B/lane. LDS dest = wave-uniform base + lane*16 (linear!).
typedef const __attribute__((address_space(1))) unsigned int gas_uint;
typedef __attribute__((address_space(3))) unsigned int las_uint;
__device__ __forceinline__ void gld16(const u16* g, u16* l) {
    __builtin_amdgcn_global_load_lds((gas_uint*)g, (las_uint*)l, 16, 0, 0);
}

__device__ __forceinline__ f32x4 mfma16(bf16x8 a, bf16x8 b, f32x4 c) {
    return __builtin_amdgcn_mfma_f32_16x16x32_bf16(a, b, c, 0, 0, 0);
}

// Q pre-scale: 1/8 (=1/sqrt(HD)) folded with log2(e) so softmax uses exp2.
#define QSCALE 0.18033688011f

// ---------------------------------------------------------------------------
// Self-detection: read first 4096 u16 of `in`. bf16 data decodes small
// (|v|<~10); fp32 data's mantissa half-words decode huge (~44% > 1e4).
// ---------------------------------------------------------------------------
__device__ __forceinline__ int self_detect(const void* in, int tid, int* sflag) {
    if (tid == 0) *sflag = 0;
    __syncthreads();
    const u16* p = (const u16*)in;
    int loc = 0;
    for (int i = tid; i < 4096; i += 256) {
        float v = fabsf(bf2f(p[i]));
        if (v < 3e38f && v > 1e4f) loc = 1;
    }
    if (loc) *sflag = 1;
    __syncthreads();
    return *sflag;
}

// ---------------------------------------------------------------------------
// Fused prep: z=0..3 -> transpose+convert weight z into Wt[z] (+bias);
// z==4 -> convert x (block p handles 4096 contiguous elems). Each block
// self-detects dtype from its own input; z==4/p==0 publishes flags[0].
// ---------------------------------------------------------------------------
__global__ __launch_bounds__(256) void prep_all(const void* w0, const void* w1,
                                                const void* w2, const void* w3,
                                                const void* b0, const void* b1,
                                                const void* b2, const void* b3,
                                                const void* xin,
                                                u16* __restrict__ wt,
                                                u16* __restrict__ b_dst,
                                                u16* __restrict__ xc,
                                                int* __restrict__ flags) {
    __shared__ int sflag;
    __shared__ u16 tile[32][33];
    const int z   = blockIdx.z;
    const int tid = threadIdx.x;
    const void* srcs[5] = {w0, w1, w2, w3, xin};
    const void* in = srcs[z];
    const int f = self_detect(in, tid, &sflag);

    if (z == 4) {
        const int p = blockIdx.y * 32 + blockIdx.x;   // 0..1023
        if (p == 0 && tid == 0) flags[0] = f;
#pragma unroll
        for (int c = 0; c < 2; ++c) {
            const size_t i = (size_t)p * 4096 + c * 2048 + tid * 8;
            if (f) {
                const float4* s4 = (const float4*)((const float*)in + i);
                float4 a = s4[0], bq = s4[1];
                uint4 o;
                o.x = bfpack(a.x, a.y);
                o.y = bfpack(a.z, a.w);
                o.z = bfpack(bq.x, bq.y);
                o.w = bfpack(bq.z, bq.w);
                *(uint4*)(xc + i) = o;
            } else {
                *(uint4*)(xc + i) = *(const uint4*)((const u16*)in + i);
            }
        }
        return;
    }

    const void* bins[4] = {b0, b1, b2, b3};
    u16* out = wt + (size_t)z * DM * DM;
    const float scale = (z == 0) ? QSCALE : 1.0f;
    const int bx = blockIdx.x * 32;
    const int by = blockIdx.y * 32;
    const int tx = tid & 31;
    const int ty = tid >> 5;
#pragma unroll
    for (int i = ty; i < 32; i += 8) {
        size_t idx = (size_t)(by + i) * DM + bx + tx;
        float v = f ? ((const float*)in)[idx] : bf2f(((const u16*)in)[idx]);
        tile[i][tx] = f2bf(v * scale);
    }
    __syncthreads();
#pragma unroll
    for (int i = ty; i < 32; i += 8) out[(size_t)(bx + i) * DM + by + tx] = tile[tx][i];

    if (blockIdx.x == 0 && blockIdx.y == 0) {
        const void* bi = bins[z];
        for (int i = tid; i < DM; i += 256) {
            float v = f ? ((const float*)bi)[i] : bf2f(((const u16*)bi)[i]);
            b_dst[z * DM + i] = f2bf(v * scale);
        }
    }
}

// ---------------------------------------------------------------------------
// QKV GEMM, B^T form, 128x128 tile, XCD-swizzled 1D grid (768 blocks):
// XCD x owns n-cols [3x, 3x+3) -> B-panel 768KB resident in its L2;
// consecutive j share the A row-block (3x temporal reuse).
// Outputs (always bf16): mat 0 -> Q, mat 1 -> K (row-major);
// mat 2 -> V^T directly: Vt[n*SEQ + row], packed 4-row 8B stores
// (per wave each 128B Vt line is fully covered -> clean L2 writeback).
// ---------------------------------------------------------------------------
__global__ __launch_bounds__(256, 2) void gemm_qkv(const u16* __restrict__ A,
                                                   const u16* __restrict__ Bt,
                                                   const u16* __restrict__ bias,
                                                   u16* __restrict__ Qo,
                                                   u16* __restrict__ Ko,
                                                   u16* __restrict__ VtO) {
    __shared__ u16 As[128 * 32];
    __shared__ u16 Bs[128 * 32];
    const int tid  = threadIdx.x;
    const int lane = tid & 63;
    const int w    = tid >> 6;
    const int m    = lane & 15;
    const int quad = lane >> 4;
    const int wr   = w >> 1;
    const int wc   = w & 1;

    const int b   = blockIdx.x;
    const int x   = b & 7;
    const int j   = b >> 3;              // 0..95
    const int nb  = (x * 3 + j % 3) * 128;
    const int mb  = (j / 3) * 128;
    const int mat = nb >> 10;
    const int lnb = nb & 1023;

    f32x4 acc[4][4] = {};

    for (int kb = 0; kb < DM; kb += 32) {
        __syncthreads();
#pragma unroll
        for (int i = 0; i < 2; ++i) {
            const int Lb = i * 256 + w * 64;
            const int L  = Lb + lane;
            const int row = L >> 2, cb = L & 3;
            gld16(&A[(size_t)(mb + row) * DM + kb + cb * 8], &As[Lb * 8]);
            gld16(&Bt[(size_t)(nb + row) * DM + kb + cb * 8], &Bs[Lb * 8]);
        }
        __syncthreads();

        bf16x8 af[4];
#pragma unroll
        for (int mt = 0; mt < 4; ++mt)
            af[mt] = *(const bf16x8*)&As[(wr * 64 + mt * 16 + m) * 32 + quad * 8];
#pragma unroll
        for (int ct = 0; ct < 4; ++ct) {
            bf16x8 bfr = *(const bf16x8*)&Bs[(wc * 64 + ct * 16 + m) * 32 + quad * 8];
#pragma unroll
            for (int mt = 0; mt < 4; ++mt)
                acc[mt][ct] = mfma16(af[mt], bfr, acc[mt][ct]);
        }
    }

    if (mat < 2) {
        u16* C = mat ? Ko : Qo;
#pragma unroll
        for (int ct = 0; ct < 4; ++ct) {
            float bv = bf2f(bias[nb + wc * 64 + ct * 16 + m]);
#pragma unroll
            for (int mt = 0; mt < 4; ++mt)
#pragma unroll
                for (int r = 0; r < 4; ++r) {
                    int row = mb + wr * 64 + mt * 16 + quad * 4 + r;
                    C[(size_t)row * DM + lnb + wc * 64 + ct * 16 + m] =
                        f2bf(acc[mt][ct][r] + bv);
                }
        }
    } else {
        // V^T: col n -> Vt row, rows packed 4-at-a-time (8B stores)
#pragma unroll
        for (int ct = 0; ct < 4; ++ct) {
            const int n = lnb + wc * 64 + ct * 16 + m;
            float bv = bf2f(bias[nb + wc * 64 + ct * 16 + m]);
#pragma unroll
            for (int mt = 0; mt < 4; ++mt) {
                const int rowb = mb + wr * 64 + mt * 16 + quad * 4;
                uint2 pk;
                pk.x = bfpack(acc[mt][ct][0] + bv, acc[mt][ct][1] + bv);
                pk.y = bfpack(acc[mt][ct][2] + bv, acc[mt][ct][3] + bv);
                *(uint2*)&VtO[(size_t)n * SEQ + rowb] = pk;
            }
        }
    }
}

// ---------------------------------------------------------------------------
// Out-projection GEMM: 128x64 tiles, XCD-swizzled 1D grid (512 blocks, 2/CU).
// Output dtype per flags[0].
// ---------------------------------------------------------------------------
__global__ __launch_bounds__(256, 2) void gemm_n64(const u16* __restrict__ A,
                                                   const u16* __restrict__ Bt,
                                                   const u16* __restrict__ bias,
                                                   void* __restrict__ C,
                                                   const int* __restrict__ flags) {
    __shared__ u16 As[128 * 32];
    __shared__ u16 Bs[64 * 32];
    const int f    = flags[0];
    const int tid  = threadIdx.x;
    const int lane = tid & 63;
    const int w    = tid >> 6;
    const int m    = lane & 15;
    const int quad = lane >> 4;

    const int b  = blockIdx.x;
    const int x  = b & 7;
    const int j  = b >> 3;               // 0..63
    const int nb = (x * 2 + (j & 1)) * 64;
    const int mb = (j >> 1) * 128;

    f32x4 acc[2][4] = {};

    for (int kb = 0; kb < DM; kb += 32) {
        __syncthreads();
#pragma unroll
        for (int i = 0; i < 2; ++i) {
            const int Lb = (2 * w + i) * 64;
            const int L  = Lb + lane;
            const int row = L >> 2, cb = L & 3;
            gld16(&A[(size_t)(mb + row) * DM + kb + cb * 8], &As[Lb * 8]);
        }
        {
            const int L = w * 64 + lane;
            const int row = L >> 2, cb = L & 3;
            gld16(&Bt[(size_t)(nb + row) * DM + kb + cb * 8], &Bs[w * 512]);
        }
        __syncthreads();

        bf16x8 af[2];
#pragma unroll
        for (int mt = 0; mt < 2; ++mt)
            af[mt] = *(const bf16x8*)&As[(w * 32 + mt * 16 + m) * 32 + quad * 8];
#pragma unroll
        for (int ct = 0; ct < 4; ++ct) {
            bf16x8 bfr = *(const bf16x8*)&Bs[(ct * 16 + m) * 32 + quad * 8];
#pragma unroll
            for (int mt = 0; mt < 2; ++mt)
                acc[mt][ct] = mfma16(af[mt], bfr, acc[mt][ct]);
        }
    }

#pragma unroll
    for (int ct = 0; ct < 4; ++ct) {
        float bv = bf2f(bias[nb + ct * 16 + m]);
#pragma unroll
        for (int mt = 0; mt < 2; ++mt) {
#pragma unroll
            for (int r = 0; r < 4; ++r) {
                int row = mb + w * 32 + mt * 16 + quad * 4 + r;
                size_t idx = (size_t)row * DM + nb + ct * 16 + m;
                float v = acc[mt][ct][r] + bv;
                if (f) ((float*)C)[idx] = v;
                else   ((u16*)C)[idx]   = f2bf(v);
            }
        }
    }
}

// ===========================================================================
// Transposed-S flash attention, 3-way split-K, BK=128. 768 blocks.
// (unchanged from round 10 — 59.7 us, MfmaUtil 22.6%)
// ===========================================================================
__global__ __launch_bounds__(256, 2) void attn_split(const u16* __restrict__ Qb,
                                                     const u16* __restrict__ Kb,
                                                     const u16* __restrict__ Vt,
                                                     u16* __restrict__ slot0,
                                                     u16* __restrict__ slot1,
                                                     u16* __restrict__ slot2,
                                                     float* __restrict__ l0,
                                                     float* __restrict__ l1,
                                                     float* __restrict__ l2) {
    __shared__ u16 Ks[2][128 * 64];
    __shared__ u16 Vs[2][64 * 128];

    const int tid  = threadIdx.x;
    const int lane = tid & 63;
    const int w    = tid >> 6;
    const int m    = lane & 15;
    const int quad = lane >> 4;
    const int l3   = lane >> 3;
    const int l4   = lane >> 4;
    const int m7   = m & 7;
    const int cxk  = ((lane & 7) ^ l3) * 8;

    const int b    = blockIdx.x;
    const int x    = b & 7;
    const int u    = b >> 3;
    const int qt2  = 15 - (u / 6);
    const int v6   = u % 6;
    const int head = 2 * x + (v6 / 3);
    const int part = v6 % 3;
    const int hc   = head * HDIM;
    const int n128 = 2 * qt2 + 2;
    const int k0t  = part * n128 / 3;
    const int k1t  = (part + 1) * n128 / 3 - 1;

    const int qw = qt2 * 256 + w * 64;
    const int dw = qw >> 6;

    bf16x8 qf[4][2];
#pragma unroll
    for (int qt4 = 0; qt4 < 4; ++qt4)
#pragma unroll
        for (int c = 0; c < 2; ++c)
            qf[qt4][c] = *(const bf16x8*)&Qb[(size_t)(qw + qt4 * 16 + m) * DM + hc + c * 32 + quad * 8];

    f32x4 o_acc[4][4] = {};
    float l_part[4] = {0.f, 0.f, 0.f, 0.f};

#pragma unroll
    for (int i = 0; i < 4; ++i) {
        const int kr = w * 32 + i * 8 + l3;
        gld16(&Kb[(size_t)(k0t * 128 + kr) * DM + hc + cxk], &Ks[0][(w * 32 + i * 8) * 64]);
        const int vr = w * 16 + i * 4 + l4;
        const int cxv = ((lane & 15) ^ ((i * 4 + l4) & 7)) * 8;
        gld16(&Vt[(size_t)(hc + vr) * SEQ + k0t * 128 + cxv], &Vs[0][(w * 16 + i * 4) * 128]);
    }

    for (int kt = k0t; kt <= k1t; ++kt) {
        const int cur = (kt - k0t) & 1;
        __syncthreads();

        if (kt < k1t) {
            const int nbf = 1 - cur;
            const int nkt = kt + 1;
#pragma unroll
            for (int i = 0; i < 4; ++i) {
                const int kr = w * 32 + i * 8 + l3;
                gld16(&Kb[(size_t)(nkt * 128 + kr) * DM + hc + cxk], &Ks[nbf][(w * 32 + i * 8) * 64]);
                const int vr = w * 16 + i * 4 + l4;
                const int cxv = ((lane & 15) ^ ((i * 4 + l4) & 7)) * 8;
                gld16(&Vt[(size_t)(hc + vr) * SEQ + nkt * 128 + cxv], &Vs[nbf][(w * 16 + i * 4) * 128]);
            }
        }

        const u16* ksb = Ks[cur];
        const u16* vsb = Vs[cur];

#pragma unroll
        for (int h = 0; h < 2; ++h) {
            const int t64 = kt * 2 + h;
            if (t64 > dw) continue;

#pragma unroll
            for (int p = 0; p < 2; ++p) {
                const int ph = 2 * h + p;
                uint4 pa_raw[4];

#pragma unroll
                for (int stt = 0; stt < 2; ++stt) {
                    const int st = ph * 2 + stt;
                    bf16x8 kf[2];
#pragma unroll
                    for (int c = 0; c < 2; ++c)
                        kf[c] = *(const bf16x8*)&ksb[(st * 16 + m) * 64 + (((c * 4 + quad) ^ m7) * 8)];

                    f32x4 sc[4];
#pragma unroll
                    for (int qt4 = 0; qt4 < 4; ++qt4) {
                        f32x4 a = {};
                        a = mfma16(kf[0], qf[qt4][0], a);
                        a = mfma16(kf[1], qf[qt4][1], a);
                        sc[qt4] = a;
                    }

                    if (t64 == dw) {
                        const int stl = 2 * p + stt;
#pragma unroll
                        for (int qt4 = 0; qt4 < 4; ++qt4)
#pragma unroll
                            for (int r = 0; r < 4; ++r) {
                                float pp = __builtin_amdgcn_exp2f(sc[qt4][r]);
                                sc[qt4][r] = (stl * 16 + quad * 4 + r > qt4 * 16 + m) ? 0.f : pp;
                            }
                    } else {
#pragma unroll
                        for (int qt4 = 0; qt4 < 4; ++qt4)
#pragma unroll
                            for (int r = 0; r < 4; ++r)
                                sc[qt4][r] = __builtin_amdgcn_exp2f(sc[qt4][r]);
                    }

#pragma unroll
                    for (int qt4 = 0; qt4 < 4; ++qt4) {
                        l_part[qt4] += sc[qt4][0] + sc[qt4][1] + sc[qt4][2] + sc[qt4][3];
                        const u32 pk0 = bfpack(sc[qt4][0], sc[qt4][1]);
                        const u32 pk1 = bfpack(sc[qt4][2], sc[qt4][3]);
                        if (stt == 0) { pa_raw[qt4].x = pk0; pa_raw[qt4].y = pk1; }
                        else          { pa_raw[qt4].z = pk0; pa_raw[qt4].w = pk1; }
                    }
                }

                bf16x8 pa[4];
#pragma unroll
                for (int qt4 = 0; qt4 < 4; ++qt4) __builtin_memcpy(&pa[qt4], &pa_raw[qt4], 16);

#pragma unroll
                for (int dt = 0; dt < 4; ++dt) {
                    const int base = (dt * 16 + m) * 128;
                    const int clo = ((4 * ph + (quad >> 1)) ^ m7) * 8 + (quad & 1) * 4;
                    const int chi = ((4 * ph + 2 + (quad >> 1)) ^ m7) * 8 + (quad & 1) * 4;
                    uint2 vlo = *(const uint2*)&vsb[base + clo];
                    uint2 vhi = *(const uint2*)&vsb[base + chi];
                    uint4 t;
                    t.x = vlo.x; t.y = vlo.y; t.z = vhi.x; t.w = vhi.y;
                    bf16x8 vf;
                    __builtin_memcpy(&vf, &t, 16);
#pragma unroll
                    for (int qt4 = 0; qt4 < 4; ++qt4)
                        o_acc[qt4][dt] = mfma16(pa[qt4], vf, o_acc[qt4][dt]);
                }
            }
        }
    }

#pragma unroll
    for (int qt4 = 0; qt4 < 4; ++qt4) {
        l_part[qt4] += __shfl_xor(l_part[qt4], 16, 64);
        l_part[qt4] += __shfl_xor(l_part[qt4], 32, 64);
    }

    u16*   dst = (part == 0) ? slot0 : ((part == 1) ? slot1 : slot2);
    float* lb  = (part == 0) ? l0 : ((part == 1) ? l1 : l2);
#pragma unroll
    for (int qt4 = 0; qt4 < 4; ++qt4)
#pragma unroll
        for (int dt = 0; dt < 4; ++dt)
#pragma unroll
            for (int r = 0; r < 4; ++r) {
                int row = qw + qt4 * 16 + quad * 4 + r;
                dst[(size_t)row * DM + hc + dt * 16 + m] = f2bf(o_acc[qt4][dt][r]);
            }
    if (lane < 16) {
#pragma unroll
        for (int qt4 = 0; qt4 < 4; ++qt4)
            lb[head * SEQ + qw + qt4 * 16 + lane] = l_part[qt4];
    }
}

// Merge thirds in place: s0 = (s0+s1+s2) / (l0+l1+l2), all rows.
__global__ __launch_bounds__(256) void merge_k(u16* __restrict__ s0,
                                               const u16* __restrict__ s1,
                                               const u16* __restrict__ s2,
                                               const float* __restrict__ l0,
                                               const float* __restrict__ l1,
                                               const float* __restrict__ l2) {
    const int gid = blockIdx.x * 256 + threadIdx.x;  // SEQ*128 threads
    const int rl = gid >> 7;
    const int cg = gid & 127;
    const int h  = cg >> 3;
    const float inv = 1.0f / (l0[h * SEQ + rl] + l1[h * SEQ + rl] + l2[h * SEQ + rl]);
    uint4 va = *(const uint4*)(s0 + (size_t)rl * DM + cg * 8);
    uint4 vb = *(const uint4*)(s1 + (size_t)rl * DM + cg * 8);
    uint4 vc = *(const uint4*)(s2 + (size_t)rl * DM + cg * 8);
    const u16* a16 = (const u16*)&va;
    const u16* b16 = (const u16*)&vb;
    const u16* c16 = (const u16*)&vc;
    u16 oo[8];
#pragma unroll
    for (int i = 0; i < 8; ++i)
        oo[i] = f2bf((bf2f(a16[i]) + bf2f(b16[i]) + bf2f(c16[i])) * inv);
    *(uint4*)(s0 + (size_t)rl * DM + cg * 8) = *(const uint4*)&oo[0];
}

// ---------------------------------------------------------------------------
extern "C" void kernel_launch(void* const* d_in, const int* in_sizes, int n_in,
                              void* d_out, int out_size, void* d_ws, size_t ws_size,
                              hipStream_t stream) {
    (void)in_sizes; (void)n_in; (void)out_size; (void)ws_size;

    u16* ws    = (u16*)d_ws;
    int* flags = (int*)d_ws;                       // [0]=dtype (prep-published)
    u16* xc    = ws + 64;                          // SEQ*DM; dead after gemm_qkv -> slotC
    u16* Wtqkv = xc + (size_t)SEQ * DM;            // 3*DM*DM; dead after gemm_qkv -> l0/1/2
    u16* Wto   = Wtqkv + (size_t)3 * DM * DM;      // DM*DM (live to the end)
    u16* bqkv  = Wto + (size_t)DM * DM;            // 3*DM
    u16* boc   = bqkv + 3 * DM;                    // DM
    u16* Qb    = boc + DM;                         // SEQ*DM
    u16* Kb    = Qb + (size_t)SEQ * DM;            // SEQ*DM
    u16* Vt_g  = Kb + (size_t)SEQ * DM;            // SEQ*DM (V^T, written by gemm_qkv)
    u16* ab    = Vt_g + (size_t)SEQ * DM;          // SEQ*DM (slot0 -> merged O)
    u16* slotB = ab + (size_t)SEQ * DM;            // SEQ*DM (slot1)
    u16* slotC = xc;                               // overlays dead xc
    float* l0f = (float*)Wtqkv;                    // NH*SEQ each (overlay dead Wtqkv)
    float* l1f = l0f + NH * SEQ;
    float* l2f = l1f + NH * SEQ;
    // total ~56 MB, same footprint as rounds 5-10. 5 launches (was 8).

    prep_all<<<dim3(32, 32, 5), 256, 0, stream>>>(
        d_in[1], d_in[3], d_in[5], d_in[7],
        d_in[2], d_in[4], d_in[6], d_in[8],
        d_in[0], Wtqkv, bqkv, xc, flags);

    gemm_qkv<<<dim3(768), 256, 0, stream>>>(xc, Wtqkv, bqkv, Qb, Kb, Vt_g);

    attn_split<<<dim3(768), 256, 0, stream>>>(Qb, Kb, Vt_g, ab, slotB, slotC,
                                              l0f, l1f, l2f);

    merge_k<<<dim3(SEQ * 128 / 256), 256, 0, stream>>>(ab, slotB, slotC, l0f, l1f, l2f);

    gemm_n64<<<dim3(512), 256, 0, stream>>>(ab, Wto, boc, d_out, flags);
}

// Round 12
// 217.190 us; speedup vs baseline: 1.0333x; 1.0333x over previous
//
#include <hip/hip_runtime.h>

// B=1, S=4096, D=1024, H=16, HD=64. I/O dtype self-detected (fp32 vs bf16).
#define SEQ 4096
#define DM  1024
#define NH  16
#define HDIM 64

typedef unsigned short u16;
typedef unsigned int   u32;
typedef __bf16 bf16x8 __attribute__((ext_vector_type(8)));
typedef float f32x4 __attribute__((ext_vector_type(4)));

__device__ __forceinline__ float bf2f(u16 u) {
    unsigned v = ((unsigned)u) << 16;
    float f;
    __builtin_memcpy(&f, &v, 4);
    return f;
}
__device__ __forceinline__ u16 f2bf(float f) {
    unsigned u;
    __builtin_memcpy(&u, &f, 4);
    return (u16)((u + 0x7fffu + ((u >> 16) & 1u)) >> 16);  // RNE
}
__device__ __forceinline__ u32 bfpack(float a, float b) {
    u32 ua, ub;
    __builtin_memcpy(&ua, &a, 4);
    __builtin_memcpy(&ub, &b, 4);
    return ((ua + 0x8000u) >> 16) | ((ub + 0x8000u) & 0xffff0000u);
}

// async global->LDS, 16B/lane. LDS dest = wave-uniform base + lane*16 (linear!).
typedef const __attribute__((address_space(1))) unsigned int gas_uint;
typedef __attribute__((address_space(3))) unsigned int las_uint;
__device__ __forceinline__ void gld16(const u16* g, u16* l) {
    __builtin_amdgcn_global_load_lds((gas_uint*)g, (las_uint*)l, 16, 0, 0);
}

__device__ __forceinline__ f32x4 mfma16(bf16x8 a, bf16x8 b, f32x4 c) {
    return __builtin_amdgcn_mfma_f32_16x16x32_bf16(a, b, c, 0, 0, 0);
}

// Q pre-scale: 1/8 (=1/sqrt(HD)) folded with log2(e) so softmax uses exp2.
#define QSCALE 0.18033688011f

// ---------------------------------------------------------------------------
// Self-detection: read first 4096 u16 of `in`. bf16 data decodes small;
// fp32 data's mantissa half-words decode huge (~44% > 1e4).
// ---------------------------------------------------------------------------
__device__ __forceinline__ int self_detect(const void* in, int tid, int* sflag) {
    if (tid == 0) *sflag = 0;
    __syncthreads();
    const u16* p = (const u16*)in;
    int loc = 0;
    for (int i = tid; i < 4096; i += 256) {
        float v = fabsf(bf2f(p[i]));
        if (v < 3e38f && v > 1e4f) loc = 1;
    }
    if (loc) *sflag = 1;
    __syncthreads();
    return *sflag;
}

// ---------------------------------------------------------------------------
// Fused prep: z=0..3 -> transpose+convert weight z into Wt[z] (+bias);
// z==4 -> convert x. Each block self-detects dtype; z==4/p==0 publishes flags.
// ---------------------------------------------------------------------------
__global__ __launch_bounds__(256) void prep_all(const void* w0, const void* w1,
                                                const void* w2, const void* w3,
                                                const void* b0, const void* b1,
                                                const void* b2, const void* b3,
                                                const void* xin,
                                                u16* __restrict__ wt,
                                                u16* __restrict__ b_dst,
                                                u16* __restrict__ xc,
                                                int* __restrict__ flags) {
    __shared__ int sflag;
    __shared__ u16 tile[32][33];
    const int z   = blockIdx.z;
    const int tid = threadIdx.x;
    const void* srcs[5] = {w0, w1, w2, w3, xin};
    const void* in = srcs[z];
    const int f = self_detect(in, tid, &sflag);

    if (z == 4) {
        const int p = blockIdx.y * 32 + blockIdx.x;   // 0..1023
        if (p == 0 && tid == 0) flags[0] = f;
#pragma unroll
        for (int c = 0; c < 2; ++c) {
            const size_t i = (size_t)p * 4096 + c * 2048 + tid * 8;
            if (f) {
                const float4* s4 = (const float4*)((const float*)in + i);
                float4 a = s4[0], bq = s4[1];
                uint4 o;
                o.x = bfpack(a.x, a.y);
                o.y = bfpack(a.z, a.w);
                o.z = bfpack(bq.x, bq.y);
                o.w = bfpack(bq.z, bq.w);
                *(uint4*)(xc + i) = o;
            } else {
                *(uint4*)(xc + i) = *(const uint4*)((const u16*)in + i);
            }
        }
        return;
    }

    const void* bins[4] = {b0, b1, b2, b3};
    u16* out = wt + (size_t)z * DM * DM;
    const float scale = (z == 0) ? QSCALE : 1.0f;
    const int bx = blockIdx.x * 32;
    const int by = blockIdx.y * 32;
    const int tx = tid & 31;
    const int ty = tid >> 5;
#pragma unroll
    for (int i = ty; i < 32; i += 8) {
        size_t idx = (size_t)(by + i) * DM + bx + tx;
        float v = f ? ((const float*)in)[idx] : bf2f(((const u16*)in)[idx]);
        tile[i][tx] = f2bf(v * scale);
    }
    __syncthreads();
#pragma unroll
    for (int i = ty; i < 32; i += 8) out[(size_t)(bx + i) * DM + by + tx] = tile[tx][i];

    if (blockIdx.x == 0 && blockIdx.y == 0) {
        const void* bi = bins[z];
        for (int i = tid; i < DM; i += 256) {
            float v = f ? ((const float*)bi)[i] : bf2f(((const u16*)bi)[i]);
            b_dst[z * DM + i] = f2bf(v * scale);
        }
    }
}

// ---------------------------------------------------------------------------
// QKV GEMM, B^T form, 128x128 tile, BK=64 (16 iters -> half the barriers of
// BK=32). LDS rows are 128B -> XOR-chunk swizzle (chunk ^ (row&7)) folded
// into the global fetch (8-lane groups still cover one 128B line). XCD-
// swizzled 1D grid (768 blocks): XCD x owns n-cols [3x,3x+3).
// mat 0 -> Q, mat 1 -> K (row-major); mat 2 -> V^T direct (8B packed stores).
// ---------------------------------------------------------------------------
__global__ __launch_bounds__(256, 2) void gemm_qkv(const u16* __restrict__ A,
                                                   const u16* __restrict__ Bt,
                                                   const u16* __restrict__ bias,
                                                   u16* __restrict__ Qo,
                                                   u16* __restrict__ Ko,
                                                   u16* __restrict__ VtO) {
    __shared__ u16 As[128 * 64];
    __shared__ u16 Bs[128 * 64];
    const int tid  = threadIdx.x;
    const int lane = tid & 63;
    const int w    = tid >> 6;
    const int m    = lane & 15;
    const int quad = lane >> 4;
    const int wr   = w >> 1;
    const int wc   = w & 1;
    const int m7   = m & 7;

    const int b   = blockIdx.x;
    const int x   = b & 7;
    const int j   = b >> 3;              // 0..95
    const int nb  = (x * 3 + j % 3) * 128;
    const int mb  = (j / 3) * 128;
    const int mat = nb >> 10;
    const int lnb = nb & 1023;

    f32x4 acc[4][4] = {};

    for (int kb = 0; kb < DM; kb += 64) {
        __syncthreads();
#pragma unroll
        for (int i = 0; i < 4; ++i) {
            const int Lb = w * 256 + i * 64;
            const int L  = Lb + lane;
            const int row = L >> 3, cb = L & 7;
            const int gc = (cb ^ (row & 7)) * 8;
            gld16(&A[(size_t)(mb + row) * DM + kb + gc], &As[Lb * 8]);
            gld16(&Bt[(size_t)(nb + row) * DM + kb + gc], &Bs[Lb * 8]);
        }
        __syncthreads();

        bf16x8 af[4][2];
#pragma unroll
        for (int mt = 0; mt < 4; ++mt)
#pragma unroll
            for (int c = 0; c < 2; ++c)
                af[mt][c] = *(const bf16x8*)&As[(wr * 64 + mt * 16 + m) * 64 + (((c * 4 + quad) ^ m7) * 8)];
#pragma unroll
        for (int ct = 0; ct < 4; ++ct) {
            const int rb = (wc * 64 + ct * 16 + m) * 64;
            bf16x8 b0 = *(const bf16x8*)&Bs[rb + (((0 + quad) ^ m7) * 8)];
            bf16x8 b1 = *(const bf16x8*)&Bs[rb + (((4 + quad) ^ m7) * 8)];
#pragma unroll
            for (int mt = 0; mt < 4; ++mt) {
                acc[mt][ct] = mfma16(af[mt][0], b0, acc[mt][ct]);
                acc[mt][ct] = mfma16(af[mt][1], b1, acc[mt][ct]);
            }
        }
    }

    if (mat < 2) {
        u16* C = mat ? Ko : Qo;
#pragma unroll
        for (int ct = 0; ct < 4; ++ct) {
            float bv = bf2f(bias[nb + wc * 64 + ct * 16 + m]);
#pragma unroll
            for (int mt = 0; mt < 4; ++mt)
#pragma unroll
                for (int r = 0; r < 4; ++r) {
                    int row = mb + wr * 64 + mt * 16 + quad * 4 + r;
                    C[(size_t)row * DM + lnb + wc * 64 + ct * 16 + m] =
                        f2bf(acc[mt][ct][r] + bv);
                }
        }
    } else {
#pragma unroll
        for (int ct = 0; ct < 4; ++ct) {
            const int n = lnb + wc * 64 + ct * 16 + m;
            float bv = bf2f(bias[nb + wc * 64 + ct * 16 + m]);
#pragma unroll
            for (int mt = 0; mt < 4; ++mt) {
                const int rowb = mb + wr * 64 + mt * 16 + quad * 4;
                uint2 pk;
                pk.x = bfpack(acc[mt][ct][0] + bv, acc[mt][ct][1] + bv);
                pk.y = bfpack(acc[mt][ct][2] + bv, acc[mt][ct][3] + bv);
                *(uint2*)&VtO[(size_t)n * SEQ + rowb] = pk;
            }
        }
    }
}

// ---------------------------------------------------------------------------
// Out-projection, split-K-2: 512 blocks (2/CU), 128x128 tile, BK=64,
// K-half kp covers [kp*512, kp*512+512). Partials stored bf16 (|v|<~3).
// XCD x owns n-block x (B-panel 256KB resident in its L2).
// ---------------------------------------------------------------------------
__global__ __launch_bounds__(256, 2) void gemm_osplit(const u16* __restrict__ A,
                                                      const u16* __restrict__ Bt,
                                                      u16* __restrict__ P0,
                                                      u16* __restrict__ P1) {
    __shared__ u16 As[128 * 64];
    __shared__ u16 Bs[128 * 64];
    const int tid  = threadIdx.x;
    const int lane = tid & 63;
    const int w    = tid >> 6;
    const int m    = lane & 15;
    const int quad = lane >> 4;
    const int wr   = w >> 1;
    const int wc   = w & 1;
    const int m7   = m & 7;

    const int b  = blockIdx.x;
    const int x  = b & 7;
    const int j  = b >> 3;               // 0..63
    const int kp = j & 1;
    const int mb = (j >> 1) * 128;
    const int nb = x * 128;
    const int kbase = kp * 512;

    f32x4 acc[4][4] = {};

    for (int kb = 0; kb < 512; kb += 64) {
        __syncthreads();
#pragma unroll
        for (int i = 0; i < 4; ++i) {
            const int Lb = w * 256 + i * 64;
            const int L  = Lb + lane;
            const int row = L >> 3, cb = L & 7;
            const int gc = (cb ^ (row & 7)) * 8;
            gld16(&A[(size_t)(mb + row) * DM + kbase + kb + gc], &As[Lb * 8]);
            gld16(&Bt[(size_t)(nb + row) * DM + kbase + kb + gc], &Bs[Lb * 8]);
        }
        __syncthreads();

        bf16x8 af[4][2];
#pragma unroll
        for (int mt = 0; mt < 4; ++mt)
#pragma unroll
            for (int c = 0; c < 2; ++c)
                af[mt][c] = *(const bf16x8*)&As[(wr * 64 + mt * 16 + m) * 64 + (((c * 4 + quad) ^ m7) * 8)];
#pragma unroll
        for (int ct = 0; ct < 4; ++ct) {
            const int rb = (wc * 64 + ct * 16 + m) * 64;
            bf16x8 b0 = *(const bf16x8*)&Bs[rb + (((0 + quad) ^ m7) * 8)];
            bf16x8 b1 = *(const bf16x8*)&Bs[rb + (((4 + quad) ^ m7) * 8)];
#pragma unroll
            for (int mt = 0; mt < 4; ++mt) {
                acc[mt][ct] = mfma16(af[mt][0], b0, acc[mt][ct]);
                acc[mt][ct] = mfma16(af[mt][1], b1, acc[mt][ct]);
            }
        }
    }

    u16* P = kp ? P1 : P0;
#pragma unroll
    for (int ct = 0; ct < 4; ++ct)
#pragma unroll
        for (int mt = 0; mt < 4; ++mt)
#pragma unroll
            for (int r = 0; r < 4; ++r) {
                int row = mb + wr * 64 + mt * 16 + quad * 4 + r;
                P[(size_t)row * DM + nb + wc * 64 + ct * 16 + m] = f2bf(acc[mt][ct][r]);
            }
}

// Final add: out = P0 + P1 + bias, dtype per flags[0]. 8 elems/thread.
__global__ __launch_bounds__(256) void addb(const u16* __restrict__ P0,
                                            const u16* __restrict__ P1,
                                            const u16* __restrict__ bias,
                                            void* __restrict__ out,
                                            const int* __restrict__ flags) {
    const int f = flags[0];
    const size_t i = ((size_t)blockIdx.x * 256 + threadIdx.x) * 8;
    const int n = (int)(i & 1023);
    uint4 va = *(const uint4*)(P0 + i);
    uint4 vb = *(const uint4*)(P1 + i);
    const u16* a16 = (const u16*)&va;
    const u16* b16 = (const u16*)&vb;
    float v[8];
#pragma unroll
    for (int t = 0; t < 8; ++t)
        v[t] = bf2f(a16[t]) + bf2f(b16[t]) + bf2f(bias[n + t]);
    if (f) {
        float4* o4 = (float4*)((float*)out + i);
        o4[0] = make_float4(v[0], v[1], v[2], v[3]);
        o4[1] = make_float4(v[4], v[5], v[6], v[7]);
    } else {
        uint4 o;
        o.x = bfpack(v[0], v[1]);
        o.y = bfpack(v[2], v[3]);
        o.z = bfpack(v[4], v[5]);
        o.w = bfpack(v[6], v[7]);
        *(uint4*)((u16*)out + i) = o;
    }
}

// ===========================================================================
// Transposed-S flash attention, 3-way split-K, BK=128. 768 blocks.
// (unchanged from round 10 — 59.7 us, MfmaUtil 23%)
// ===========================================================================
__global__ __launch_bounds__(256, 2) void attn_split(const u16* __restrict__ Qb,
                                                     const u16* __restrict__ Kb,
                                                     const u16* __restrict__ Vt,
                                                     u16* __restrict__ slot0,
                                                     u16* __restrict__ slot1,
                                                     u16* __restrict__ slot2,
                                                     float* __restrict__ l0,
                                                     float* __restrict__ l1,
                                                     float* __restrict__ l2) {
    __shared__ u16 Ks[2][128 * 64];
    __shared__ u16 Vs[2][64 * 128];

    const int tid  = threadIdx.x;
    const int lane = tid & 63;
    const int w    = tid >> 6;
    const int m    = lane & 15;
    const int quad = lane >> 4;
    const int l3   = lane >> 3;
    const int l4   = lane >> 4;
    const int m7   = m & 7;
    const int cxk  = ((lane & 7) ^ l3) * 8;

    const int b    = blockIdx.x;
    const int x    = b & 7;
    const int u    = b >> 3;
    const int qt2  = 15 - (u / 6);
    const int v6   = u % 6;
    const int head = 2 * x + (v6 / 3);
    const int part = v6 % 3;
    const int hc   = head * HDIM;
    const int n128 = 2 * qt2 + 2;
    const int k0t  = part * n128 / 3;
    const int k1t  = (part + 1) * n128 / 3 - 1;

    const int qw = qt2 * 256 + w * 64;
    const int dw = qw >> 6;

    bf16x8 qf[4][2];
#pragma unroll
    for (int qt4 = 0; qt4 < 4; ++qt4)
#pragma unroll
        for (int c = 0; c < 2; ++c)
            qf[qt4][c] = *(const bf16x8*)&Qb[(size_t)(qw + qt4 * 16 + m) * DM + hc + c * 32 + quad * 8];

    f32x4 o_acc[4][4] = {};
    float l_part[4] = {0.f, 0.f, 0.f, 0.f};

#pragma unroll
    for (int i = 0; i < 4; ++i) {
        const int kr = w * 32 + i * 8 + l3;
        gld16(&Kb[(size_t)(k0t * 128 + kr) * DM + hc + cxk], &Ks[0][(w * 32 + i * 8) * 64]);
        const int vr = w * 16 + i * 4 + l4;
        const int cxv = ((lane & 15) ^ ((i * 4 + l4) & 7)) * 8;
        gld16(&Vt[(size_t)(hc + vr) * SEQ + k0t * 128 + cxv], &Vs[0][(w * 16 + i * 4) * 128]);
    }

    for (int kt = k0t; kt <= k1t; ++kt) {
        const int cur = (kt - k0t) & 1;
        __syncthreads();

        if (kt < k1t) {
            const int nbf = 1 - cur;
            const int nkt = kt + 1;
#pragma unroll
            for (int i = 0; i < 4; ++i) {
                const int kr = w * 32 + i * 8 + l3;
                gld16(&Kb[(size_t)(nkt * 128 + kr) * DM + hc + cxk], &Ks[nbf][(w * 32 + i * 8) * 64]);
                const int vr = w * 16 + i * 4 + l4;
                const int cxv = ((lane & 15) ^ ((i * 4 + l4) & 7)) * 8;
                gld16(&Vt[(size_t)(hc + vr) * SEQ + nkt * 128 + cxv], &Vs[nbf][(w * 16 + i * 4) * 128]);
            }
        }

        const u16* ksb = Ks[cur];
        const u16* vsb = Vs[cur];

#pragma unroll
        for (int h = 0; h < 2; ++h) {
            const int t64 = kt * 2 + h;
            if (t64 > dw) continue;

#pragma unroll
            for (int p = 0; p < 2; ++p) {
                const int ph = 2 * h + p;
                uint4 pa_raw[4];

#pragma unroll
                for (int stt = 0; stt < 2; ++stt) {
                    const int st = ph * 2 + stt;
                    bf16x8 kf[2];
#pragma unroll
                    for (int c = 0; c < 2; ++c)
                        kf[c] = *(const bf16x8*)&ksb[(st * 16 + m) * 64 + (((c * 4 + quad) ^ m7) * 8)];

                    f32x4 sc[4];
#pragma unroll
                    for (int qt4 = 0; qt4 < 4; ++qt4) {
                        f32x4 a = {};
                        a = mfma16(kf[0], qf[qt4][0], a);
                        a = mfma16(kf[1], qf[qt4][1], a);
                        sc[qt4] = a;
                    }

                    if (t64 == dw) {
                        const int stl = 2 * p + stt;
#pragma unroll
                        for (int qt4 = 0; qt4 < 4; ++qt4)
#pragma unroll
                            for (int r = 0; r < 4; ++r) {
                                float pp = __builtin_amdgcn_exp2f(sc[qt4][r]);
                                sc[qt4][r] = (stl * 16 + quad * 4 + r > qt4 * 16 + m) ? 0.f : pp;
                            }
                    } else {
#pragma unroll
                        for (int qt4 = 0; qt4 < 4; ++qt4)
#pragma unroll
                            for (int r = 0; r < 4; ++r)
                                sc[qt4][r] = __builtin_amdgcn_exp2f(sc[qt4][r]);
                    }

#pragma unroll
                    for (int qt4 = 0; qt4 < 4; ++qt4) {
                        l_part[qt4] += sc[qt4][0] + sc[qt4][1] + sc[qt4][2] + sc[qt4][3];
                        const u32 pk0 = bfpack(sc[qt4][0], sc[qt4][1]);
                        const u32 pk1 = bfpack(sc[qt4][2], sc[qt4][3]);
                        if (stt == 0) { pa_raw[qt4].x = pk0; pa_raw[qt4].y = pk1; }
                        else          { pa_raw[qt4].z = pk0; pa_raw[qt4].w = pk1; }
                    }
                }

                bf16x8 pa[4];
#pragma unroll
                for (int qt4 = 0; qt4 < 4; ++qt4) __builtin_memcpy(&pa[qt4], &pa_raw[qt4], 16);

#pragma unroll
                for (int dt = 0; dt < 4; ++dt) {
                    const int base = (dt * 16 + m) * 128;
                    const int clo = ((4 * ph + (quad >> 1)) ^ m7) * 8 + (quad & 1) * 4;
                    const int chi = ((4 * ph + 2 + (quad >> 1)) ^ m7) * 8 + (quad & 1) * 4;
                    uint2 vlo = *(const uint2*)&vsb[base + clo];
                    uint2 vhi = *(const uint2*)&vsb[base + chi];
                    uint4 t;
                    t.x = vlo.x; t.y = vlo.y; t.z = vhi.x; t.w = vhi.y;
                    bf16x8 vf;
                    __builtin_memcpy(&vf, &t, 16);
#pragma unroll
                    for (int qt4 = 0; qt4 < 4; ++qt4)
                        o_acc[qt4][dt] = mfma16(pa[qt4], vf, o_acc[qt4][dt]);
                }
            }
        }
    }

#pragma unroll
    for (int qt4 = 0; qt4 < 4; ++qt4) {
        l_part[qt4] += __shfl_xor(l_part[qt4], 16, 64);
        l_part[qt4] += __shfl_xor(l_part[qt4], 32, 64);
    }

    u16*   dst = (part == 0) ? slot0 : ((part == 1) ? slot1 : slot2);
    float* lb  = (part == 0) ? l0 : ((part == 1) ? l1 : l2);
#pragma unroll
    for (int qt4 = 0; qt4 < 4; ++qt4)
#pragma unroll
        for (int dt = 0; dt < 4; ++dt)
#pragma unroll
            for (int r = 0; r < 4; ++r) {
                int row = qw + qt4 * 16 + quad * 4 + r;
                dst[(size_t)row * DM + hc + dt * 16 + m] = f2bf(o_acc[qt4][dt][r]);
            }
    if (lane < 16) {
#pragma unroll
        for (int qt4 = 0; qt4 < 4; ++qt4)
            lb[head * SEQ + qw + qt4 * 16 + lane] = l_part[qt4];
    }
}

// Merge thirds in place: s0 = (s0+s1+s2) / (l0+l1+l2), all rows.
__global__ __launch_bounds__(256) void merge_k(u16* __restrict__ s0,
                                               const u16* __restrict__ s1,
                                               const u16* __restrict__ s2,
                                               const float* __restrict__ l0,
                                               const float* __restrict__ l1,
                                               const float* __restrict__ l2) {
    const int gid = blockIdx.x * 256 + threadIdx.x;  // SEQ*128 threads
    const int rl = gid >> 7;
    const int cg = gid & 127;
    const int h  = cg >> 3;
    const float inv = 1.0f / (l0[h * SEQ + rl] + l1[h * SEQ + rl] + l2[h * SEQ + rl]);
    uint4 va = *(const uint4*)(s0 + (size_t)rl * DM + cg * 8);
    uint4 vb = *(const uint4*)(s1 + (size_t)rl * DM + cg * 8);
    uint4 vc = *(const uint4*)(s2 + (size_t)rl * DM + cg * 8);
    const u16* a16 = (const u16*)&va;
    const u16* b16 = (const u16*)&vb;
    const u16* c16 = (const u16*)&vc;
    u16 oo[8];
#pragma unroll
    for (int i = 0; i < 8; ++i)
        oo[i] = f2bf((bf2f(a16[i]) + bf2f(b16[i]) + bf2f(c16[i])) * inv);
    *(uint4*)(s0 + (size_t)rl * DM + cg * 8) = *(const uint4*)&oo[0];
}

// ---------------------------------------------------------------------------
extern "C" void kernel_launch(void* const* d_in, const int* in_sizes, int n_in,
                              void* d_out, int out_size, void* d_ws, size_t ws_size,
                              hipStream_t stream) {
    (void)in_sizes; (void)n_in; (void)out_size; (void)ws_size;

    u16* ws    = (u16*)d_ws;
    int* flags = (int*)d_ws;                       // [0]=dtype (prep-published)
    u16* xc    = ws + 64;                          // SEQ*DM; dead after gemm_qkv -> slotC -> P0
    u16* Wtqkv = xc + (size_t)SEQ * DM;            // 3*DM*DM; dead after gemm_qkv -> l0/1/2
    u16* Wto   = Wtqkv + (size_t)3 * DM * DM;      // DM*DM (live to the end)
    u16* bqkv  = Wto + (size_t)DM * DM;            // 3*DM
    u16* boc   = bqkv + 3 * DM;                    // DM
    u16* Qb    = boc + DM;                         // SEQ*DM
    u16* Kb    = Qb + (size_t)SEQ * DM;            // SEQ*DM
    u16* Vt_g  = Kb + (size_t)SEQ * DM;            // SEQ*DM (V^T, written by gemm_qkv)
    u16* ab    = Vt_g + (size_t)SEQ * DM;          // SEQ*DM (slot0 -> merged O)
    u16* slotB = ab + (size_t)SEQ * DM;            // SEQ*DM (slot1 -> P1)
    u16* slotC = xc;                               // slot2; later P0
    float* l0f = (float*)Wtqkv;                    // NH*SEQ each (overlay dead Wtqkv)
    float* l1f = l0f + NH * SEQ;
    float* l2f = l1f + NH * SEQ;
    // total ~56 MB, same footprint as rounds 5-11. 6 launches.

    prep_all<<<dim3(32, 32, 5), 256, 0, stream>>>(
        d_in[1], d_in[3], d_in[5], d_in[7],
        d_in[2], d_in[4], d_in[6], d_in[8],
        d_in[0], Wtqkv, bqkv, xc, flags);

    gemm_qkv<<<dim3(768), 256, 0, stream>>>(xc, Wtqkv, bqkv, Qb, Kb, Vt_g);

    attn_split<<<dim3(768), 256, 0, stream>>>(Qb, Kb, Vt_g, ab, slotB, slotC,
                                              l0f, l1f, l2f);

    merge_k<<<dim3(SEQ * 128 / 256), 256, 0, stream>>>(ab, slotB, slotC, l0f, l1f, l2f);

    // Out projection: split-K-2 (bf16 partials into slotC/slotB) + add pass
    gemm_osplit<<<dim3(512), 256, 0, stream>>>(ab, Wto, slotC, slotB);
    addb<<<dim3(SEQ * DM / 2048), 256, 0, stream>>>(slotC, slotB, boc, d_out, flags);
}